// Round 13
// baseline (497.883 us; speedup 1.0000x reference)
//
#include <hip/hip_runtime.h>
#include <hip/hip_fp16.h>

#define DD 64     // feature dim
#define GG 64     // graphs per batch
#define CHUNK 16  // nodes per wave-chunk in k_agg
#define PBITS 9   // 512 nodes per coarse partition
#define PSZ 512
#define EPB 8192  // edges per histogram/sort block

typedef _Float16 half8 __attribute__((ext_vector_type(8)));
typedef float floatx4 __attribute__((ext_vector_type(4)));

// ---------------- per-block partition histogram (no global atomics) ----------
__global__ __launch_bounds__(512) void k_hist(const int* __restrict__ dst, int E,
                                              int* __restrict__ bcnt) {
    __shared__ int h[256];
    int t = threadIdx.x;
    if (t < 256) h[t] = 0;
    __syncthreads();
    int base = blockIdx.x * EPB;
    int n = min(EPB, E - base);
    for (int k = 0; k < EPB / 512; ++k) {
        int s = t + k * 512;
        if (s < n) atomicAdd(&h[dst[base + s] >> PBITS], 1);
    }
    __syncthreads();
    if (t < 256) bcnt[blockIdx.x * 256 + t] = h[t];
}

// ---------------- scan: bcnt -> per-(block,partition) bases; poffs ----------
__global__ __launch_bounds__(256) void k_scanB(int* __restrict__ bcnt, int nb,
                                               int* __restrict__ poffs,
                                               int* __restrict__ noffs,
                                               int N, int E) {
    __shared__ int sh[256];
    int t = threadIdx.x;
    int run = 0;
    for (int blk = 0; blk < nb; ++blk) {
        int v = bcnt[blk * 256 + t];
        bcnt[blk * 256 + t] = run;
        run += v;
    }
    int tot = run;
    sh[t] = tot;
    __syncthreads();
    for (int off = 1; off < 256; off <<= 1) {
        int u = (t >= off) ? sh[t - off] : 0;
        __syncthreads();
        sh[t] += u;
        __syncthreads();
    }
    int excl = sh[t] - tot;
    poffs[t] = excl;
    if (t == 0) {
        poffs[256] = E;
        noffs[N] = E;
    }
    for (int blk = 0; blk < nb; ++blk)
        bcnt[blk * 256 + t] += excl;
}

// ---------------- nodes-per-graph counts ----------------
__global__ __launch_bounds__(256) void k_count_batch(const int* __restrict__ batch, int N,
                                                     int* __restrict__ cntI) {
    __shared__ int h[GG];
    if (threadIdx.x < GG) h[threadIdx.x] = 0;
    __syncthreads();
    int i = blockIdx.x * 256 + threadIdx.x;
    if (i < N) atomicAdd(&h[batch[i]], 1);
    __syncthreads();
    if (threadIdx.x < GG) {
        int v = h[threadIdx.x];
        if (v) atomicAdd(&cntI[threadIdx.x], v);
    }
}

// ---------------- coarse sorted scatter (LDS counting sort per 8192 edges) ----
// word = src (17b) | (dst & 511) << 17 ; flush bases from bcnt (deterministic)
__global__ __launch_bounds__(512) void k_part1(const int* __restrict__ src,
                                               const int* __restrict__ dst, int E,
                                               const int* __restrict__ bcnt,
                                               unsigned* __restrict__ pairs1) {
    __shared__ unsigned stage[EPB];
    __shared__ unsigned char sbin[EPB];
    __shared__ int hist[256], binS[256], cur[256], gbase[256];
    int t = threadIdx.x;
    int base = blockIdx.x * EPB;
    int n = min(EPB, E - base);

    if (t < 256) {
        hist[t] = 0;
        gbase[t] = bcnt[blockIdx.x * 256 + t];
    }
    __syncthreads();
    for (int k = 0; k < EPB / 512; ++k) {
        int s = t + k * 512;
        if (s < n) atomicAdd(&hist[dst[base + s] >> PBITS], 1);
    }
    __syncthreads();
    int cnt = (t < 256) ? hist[t] : 0;
    for (int off = 1; off < 256; off <<= 1) {
        int v = 0;
        if (t >= off && t < 256) v = hist[t - off];
        __syncthreads();
        if (t < 256) hist[t] += v;
        __syncthreads();
    }
    if (t < 256) {
        int excl = hist[t] - cnt;
        binS[t] = excl;
        cur[t]  = excl;
    }
    __syncthreads();
    for (int k = 0; k < EPB / 512; ++k) {
        int s = t + k * 512;
        if (s < n) {
            int d = dst[base + s];
            int p = d >> PBITS;
            unsigned w = (unsigned)src[base + s] | ((unsigned)(d & (PSZ - 1)) << 17);
            int r = atomicAdd(&cur[p], 1);
            stage[r] = w;
            sbin[r]  = (unsigned char)p;
        }
    }
    __syncthreads();
    for (int k = 0; k < EPB / 512; ++k) {
        int s = t + k * 512;
        if (s < n) {
            int p = sbin[s];
            pairs1[gbase[p] + (s - binS[p])] = stage[s];
        }
    }
}

// ---------------- refine: full per-node sort within partition; emit noffs+dis -
__global__ __launch_bounds__(256) void k_part2(const unsigned* __restrict__ pairs1,
                                               const int* __restrict__ poffs,
                                               int* __restrict__ pairs2,
                                               int* __restrict__ noffs,
                                               float* __restrict__ disv, int N) {
    int p  = blockIdx.x;
    int pb = poffs[p], pe = poffs[p + 1];
    int len = pe - pb;
    __shared__ int h[PSZ];
    __shared__ int sc[256];
    int t = threadIdx.x;
    h[t] = 0;
    h[t + 256] = 0;
    __syncthreads();
    for (int s = t; s < len; s += 256)
        atomicAdd(&h[(pairs1[pb + s] >> 17) & (PSZ - 1)], 1);
    __syncthreads();
    int a  = h[2 * t];
    int b2 = h[2 * t + 1];
    sc[t] = a + b2;
    __syncthreads();
    for (int off = 1; off < 256; off <<= 1) {
        int u = (t >= off) ? sc[t - off] : 0;
        __syncthreads();
        sc[t] += u;
        __syncthreads();
    }
    int ex = sc[t] - (a + b2);
    int n0 = p * PSZ + 2 * t;
    if (n0 < N) {
        noffs[n0] = pb + ex;
        disv[n0]  = rsqrtf((float)(a + 1));
    }
    if (n0 + 1 < N) {
        noffs[n0 + 1] = pb + ex + a;
        disv[n0 + 1]  = rsqrtf((float)(b2 + 1));
    }
    __syncthreads();
    h[2 * t]     = ex;
    h[2 * t + 1] = ex + a;
    __syncthreads();
    for (int s = t; s < len; s += 256) {
        unsigned w = pairs1[pb + s];
        int r = atomicAdd(&h[(w >> 17) & (PSZ - 1)], 1);
        pairs2[pb + r] = (int)(w & 0x1FFFFu);
    }
}

// ---------------- g = fp16((x @ W) * dis[row])  — MFMA ----------------
template <bool FP16IN>
__global__ __launch_bounds__(256) void k_gemm(const void* __restrict__ xv,
                                              const float* __restrict__ W,
                                              const float* __restrict__ disv,
                                              __half* __restrict__ g, int N) {
    int lane = threadIdx.x & 63;
    int wave = (blockIdx.x * 256 + threadIdx.x) >> 6;
    int nw   = (gridDim.x * 256) >> 6;
    int col  = lane & 15;
    int krow = (lane >> 4) * 8;

    half8 bf[2][4];
#pragma unroll
    for (int s = 0; s < 2; ++s)
#pragma unroll
        for (int n = 0; n < 4; ++n)
#pragma unroll
            for (int e = 0; e < 8; ++e)
                bf[s][n][e] = (_Float16)W[(size_t)(krow + e + s * 32) * DD + n * 16 + col];

    int nch = (N + 15) >> 4;
    for (int c = wave; c < nch; c += nw) {
        int base = c * 16;
        int arow = min(base + (lane & 15), N - 1);
        half8 af[2];
        if constexpr (FP16IN) {
            const __half* xr = (const __half*)xv + (size_t)arow * DD + krow;
#pragma unroll
            for (int s = 0; s < 2; ++s)
                af[s] = *(const half8*)(xr + s * 32);
        } else {
            const float* xr = (const float*)xv + (size_t)arow * DD + krow;
#pragma unroll
            for (int s = 0; s < 2; ++s) {
                float4 lo = *(const float4*)(xr + s * 32);
                float4 hi = *(const float4*)(xr + s * 32 + 4);
                af[s][0] = (_Float16)lo.x; af[s][1] = (_Float16)lo.y;
                af[s][2] = (_Float16)lo.z; af[s][3] = (_Float16)lo.w;
                af[s][4] = (_Float16)hi.x; af[s][5] = (_Float16)hi.y;
                af[s][6] = (_Float16)hi.z; af[s][7] = (_Float16)hi.w;
            }
        }
        floatx4 acc[4] = {{0.f, 0.f, 0.f, 0.f}, {0.f, 0.f, 0.f, 0.f},
                          {0.f, 0.f, 0.f, 0.f}, {0.f, 0.f, 0.f, 0.f}};
#pragma unroll
        for (int s = 0; s < 2; ++s)
#pragma unroll
            for (int n = 0; n < 4; ++n)
                acc[n] = __builtin_amdgcn_mfma_f32_16x16x32_f16(af[s], bf[s][n],
                                                                acc[n], 0, 0, 0);
#pragma unroll
        for (int j = 0; j < 4; ++j) {
            int rr = base + (lane >> 4) * 4 + j;
            if (rr < N) {
                float dv = disv[rr];
#pragma unroll
                for (int n = 0; n < 4; ++n)
                    g[(size_t)rr * DD + n * 16 + col] = __float2half(acc[n][j] * dv);
            }
        }
    }
}

// ---------------- fused aggregate + finalize + pooling (register acc) --------
// Round-12 structure with ONE change: gather groups are 8 lanes x uint4 (16B)
// -> one wave VMEM covers 8 edges (full 128B row per group); dual-issue step
// covers 16 edges, so mean-degree nodes finish in one step. Cross-group
// combine: shfl_xor 8,16,32 on 8 accum values.
template <bool FP16OUT>
__global__ __launch_bounds__(256) void k_agg(const int* __restrict__ pairs2,
                                             const int* __restrict__ noffs,
                                             const __half* __restrict__ g,
                                             const float* __restrict__ disv,
                                             const float* __restrict__ bbias,
                                             const int* __restrict__ batch,
                                             void* __restrict__ xoutv,
                                             float* __restrict__ gacc, int N) {
    int lane = threadIdx.x & 63;
    int g8   = lane >> 3;
    int l8   = lane & 7;
    int wave = (blockIdx.x * 256 + threadIdx.x) >> 6;
    int nw   = (gridDim.x * 256) >> 6;
    int NB   = (N + CHUNK - 1) / CHUNK;
    float4 bjA = *(const float4*)&bbias[8 * l8];
    float4 bjB = *(const float4*)&bbias[8 * l8 + 4];
    float bj[8] = {bjA.x, bjA.y, bjA.z, bjA.w, bjB.x, bjB.y, bjB.z, bjB.w};
    const char* gb = (const char*)g;
    for (int bu = wave; bu < NB; bu += nw) {
        int nbase = bu * CHUNK;
        int nend  = min(nbase + CHUNK, N);
        int nn    = nend - nbase;
        int nf  = noffs[nbase + min(lane, nn)];
        int bch = batch[nbase + min(lane, nn - 1)];
        float vmax[8] = {0.f, 0.f, 0.f, 0.f, 0.f, 0.f, 0.f, 0.f};
        float vsum[8] = {0.f, 0.f, 0.f, 0.f, 0.f, 0.f, 0.f, 0.f};
        int curg = __shfl(bch, 0);
        // prologue: prefetch node 0's first edge-index block
        int ps0  = __shfl(nf, 0);
        int pcnt = __shfl(nf, 1) - ps0;
        int pkpre = (lane < min(pcnt, 64)) ? pairs2[ps0 + lane] : 0;
        for (int i = 0; i < nn; ++i) {
            int pk   = pkpre;
            int s0   = ps0;
            int cnt  = pcnt;
            if (i + 1 < nn) {   // prefetch next node's block (independent of gathers)
                int ns0  = __shfl(nf, i + 1);
                int ncnt = __shfl(nf, i + 2) - ns0;
                pkpre = (lane < min(ncnt, 64)) ? pairs2[ns0 + lane] : 0;
                ps0 = ns0;
                pcnt = ncnt;
            }
            float acc[8] = {0.f, 0.f, 0.f, 0.f, 0.f, 0.f, 0.f, 0.f};
            if (g8 == 0) {   // self-loop row
                uint4 rv = *(const uint4*)(gb + ((size_t)(nbase + i) * 128 + l8 * 16));
                float2 f0 = __half22float2(*(const __half2*)&rv.x);
                float2 f1 = __half22float2(*(const __half2*)&rv.y);
                float2 f2 = __half22float2(*(const __half2*)&rv.z);
                float2 f3 = __half22float2(*(const __half2*)&rv.w);
                acc[0] = f0.x; acc[1] = f0.y; acc[2] = f1.x; acc[3] = f1.y;
                acc[4] = f2.x; acc[5] = f2.y; acc[6] = f3.x; acc[7] = f3.y;
            }
            int kk0 = min(cnt, 64);
            int j = 0;
            for (; j + 16 <= kk0; j += 16) {   // guard-free dual-issue: 16 edges/step
                int sA = __shfl(pk, j + g8);
                int sB = __shfl(pk, j + 8 + g8);
                uint4 rA = *(const uint4*)(gb + ((size_t)sA * 128 + l8 * 16));
                uint4 rB = *(const uint4*)(gb + ((size_t)sB * 128 + l8 * 16));
                float2 a0 = __half22float2(*(const __half2*)&rA.x);
                float2 a1 = __half22float2(*(const __half2*)&rA.y);
                float2 a2 = __half22float2(*(const __half2*)&rA.z);
                float2 a3 = __half22float2(*(const __half2*)&rA.w);
                float2 b0 = __half22float2(*(const __half2*)&rB.x);
                float2 b1 = __half22float2(*(const __half2*)&rB.y);
                float2 b2 = __half22float2(*(const __half2*)&rB.z);
                float2 b3 = __half22float2(*(const __half2*)&rB.w);
                acc[0] += a0.x + b0.x; acc[1] += a0.y + b0.y;
                acc[2] += a1.x + b1.x; acc[3] += a1.y + b1.y;
                acc[4] += a2.x + b2.x; acc[5] += a2.y + b2.y;
                acc[6] += a3.x + b3.x; acc[7] += a3.y + b3.y;
            }
            for (; j < kk0; j += 8) {          // guarded remainder: 8 edges/step
                int idx  = j + g8;
                int sidx = __shfl(pk, min(idx, kk0 - 1));
                if (idx < kk0) {
                    uint4 rv = *(const uint4*)(gb + ((size_t)sidx * 128 + l8 * 16));
                    float2 f0 = __half22float2(*(const __half2*)&rv.x);
                    float2 f1 = __half22float2(*(const __half2*)&rv.y);
                    float2 f2 = __half22float2(*(const __half2*)&rv.z);
                    float2 f3 = __half22float2(*(const __half2*)&rv.w);
                    acc[0] += f0.x; acc[1] += f0.y; acc[2] += f1.x; acc[3] += f1.y;
                    acc[4] += f2.x; acc[5] += f2.y; acc[6] += f3.x; acc[7] += f3.y;
                }
            }
            // rare tail: degree > 64
            for (int k = 64; k < cnt; k += 64) {
                int kk = min(cnt - k, 64);
                int pkx = (lane < kk) ? pairs2[s0 + k + lane] : 0;
                for (int jj = 0; jj < kk; jj += 8) {
                    int idx  = jj + g8;
                    int sidx = __shfl(pkx, min(idx, kk - 1));
                    if (idx < kk) {
                        uint4 rv = *(const uint4*)(gb + ((size_t)sidx * 128 + l8 * 16));
                        float2 f0 = __half22float2(*(const __half2*)&rv.x);
                        float2 f1 = __half22float2(*(const __half2*)&rv.y);
                        float2 f2 = __half22float2(*(const __half2*)&rv.z);
                        float2 f3 = __half22float2(*(const __half2*)&rv.w);
                        acc[0] += f0.x; acc[1] += f0.y; acc[2] += f1.x; acc[3] += f1.y;
                        acc[4] += f2.x; acc[5] += f2.y; acc[6] += f3.x; acc[7] += f3.y;
                    }
                }
            }
#pragma unroll
            for (int m = 0; m < 8; ++m) {
                acc[m] += __shfl_xor(acc[m], 8);
                acc[m] += __shfl_xor(acc[m], 16);
                acc[m] += __shfl_xor(acc[m], 32);
            }
            float dv = disv[nbase + i];
            float v[8];
#pragma unroll
            for (int m = 0; m < 8; ++m)
                v[m] = fmaxf(fmaf(dv, acc[m], bj[m]), 0.f);
            if (g8 == 0) {
                if constexpr (FP16OUT) {
                    __half2 h0 = __float22half2_rn({v[0], v[1]});
                    __half2 h1 = __float22half2_rn({v[2], v[3]});
                    __half2 h2 = __float22half2_rn({v[4], v[5]});
                    __half2 h3 = __float22half2_rn({v[6], v[7]});
                    uint4 pkd = {*(unsigned*)&h0, *(unsigned*)&h1,
                                 *(unsigned*)&h2, *(unsigned*)&h3};
                    *(uint4*)((__half*)xoutv + (size_t)(nbase + i) * DD + 8 * l8) = pkd;
                } else {
                    float* op = (float*)xoutv + (size_t)(nbase + i) * DD + 8 * l8;
                    *(float4*)op       = float4{v[0], v[1], v[2], v[3]};
                    *(float4*)(op + 4) = float4{v[4], v[5], v[6], v[7]};
                }
            }
            int gid = __shfl(bch, i);
            if (gid != curg) {
                if (g8 == 0) {
#pragma unroll
                    for (int m = 0; m < 8; ++m)
                        atomicMax((unsigned*)&gacc[curg * 128 + 8 * l8 + m],
                                  __float_as_uint(vmax[m]));
#pragma unroll
                    for (int m = 0; m < 8; ++m)
                        atomicAdd(&gacc[curg * 128 + 64 + 8 * l8 + m], vsum[m]);
                }
#pragma unroll
                for (int m = 0; m < 8; ++m) { vmax[m] = 0.f; vsum[m] = 0.f; }
                curg = gid;
            }
#pragma unroll
            for (int m = 0; m < 8; ++m) {
                vmax[m] = fmaxf(vmax[m], v[m]);
                vsum[m] += v[m];
            }
        }
        if (g8 == 0) {
#pragma unroll
            for (int m = 0; m < 8; ++m)
                atomicMax((unsigned*)&gacc[curg * 128 + 8 * l8 + m],
                          __float_as_uint(vmax[m]));
#pragma unroll
            for (int m = 0; m < 8; ++m)
                atomicAdd(&gacc[curg * 128 + 64 + 8 * l8 + m], vsum[m]);
        }
    }
}

// ---------------- fold per-layer pool into running total; clear gacc ---------
__global__ __launch_bounds__(256) void k_pool(float* __restrict__ gacc,
                                              float* __restrict__ gtot,
                                              const int* __restrict__ cntI) {
    int i = blockIdx.x * 256 + threadIdx.x;
    if (i < GG * 2 * DD) {
        int gidx = i >> 7;
        int j    = i & 127;
        float v  = gacc[i];
        if (j >= DD) v = v / (float)cntI[gidx];
        gtot[i] += v;
        gacc[i] = 0.f;
    }
}

__global__ __launch_bounds__(256) void k_copy(const float* __restrict__ srcp,
                                              float* __restrict__ dstp, int n) {
    int i = blockIdx.x * 256 + threadIdx.x;
    if (i < n) dstp[i] = srcp[i];
}

extern "C" void kernel_launch(void* const* d_in, const int* in_sizes, int n_in,
                              void* d_out, int out_size, void* d_ws, size_t ws_size,
                              hipStream_t stream) {
    const float* x     = (const float*)d_in[0];
    const int*   ei    = (const int*)d_in[1];
    const int*   batch = (const int*)d_in[2];

    int N = in_sizes[0] / DD;
    int E = in_sizes[1] / 2;
    const int* src = ei;
    const int* dst = ei + E;

    size_t nd  = (size_t)N * DD;
    int NPART  = (N + PSZ - 1) >> PBITS;
    int NB     = (N + CHUNK - 1) / CHUNK;
    int nb     = (E + EPB - 1) / EPB;

    float*    ws     = (float*)d_ws;
    float*    bufX   = ws;                            // N*DD (f32-sized; fp16 used)
    __half*   bufX16 = (__half*)bufX;
    __half*   bufG   = (__half*)(ws + nd);            // N*DD fp16
    float*    disv   = ws + nd + nd / 2;              // N
    float*    gacc   = disv + N;                      // GG*2*DD
    float*    gtot   = gacc + GG * 2 * DD;            // GG*2*DD
    int*      cntI   = (int*)(gtot + GG * 2 * DD);    // GG
    int*      poffs  = cntI + GG;                     // 257
    int*      noffs  = poffs + 257;                   // N+1
    int*      bcnt   = noffs + N + 1;                 // nb*256
    unsigned* pairs1 = (unsigned*)(bcnt + nb * 256);  // E
    int*      pairs2 = (int*)(pairs1 + E);            // E

    hipMemsetAsync(gacc, 0, (size_t)GG * 2 * DD * sizeof(float), stream);
    hipMemsetAsync(gtot, 0, (size_t)GG * 2 * DD * sizeof(float), stream);
    hipMemsetAsync(cntI, 0, (size_t)GG * sizeof(int), stream);

    k_hist<<<nb, 512, 0, stream>>>(dst, E, bcnt);
    k_scanB<<<1, 256, 0, stream>>>(bcnt, nb, poffs, noffs, N, E);
    k_count_batch<<<(N + 255) / 256, 256, 0, stream>>>(batch, N, cntI);
    k_part1<<<nb, 512, 0, stream>>>(src, dst, E, bcnt, pairs1);
    k_part2<<<NPART, 256, 0, stream>>>(pairs1, poffs, pairs2, noffs, disv, N);

    int aggGrid = (NB + 3) / 4;

    // layer 0: f32 in -> fp16 intermediate out
    k_gemm<false><<<400, 256, 0, stream>>>(x, (const float*)d_in[3], disv, bufG, N);
    k_agg<true><<<aggGrid, 256, 0, stream>>>(pairs2, noffs, bufG, disv,
                                             (const float*)d_in[4], batch, bufX16,
                                             gacc, N);
    k_pool<<<(GG * 2 * DD + 255) / 256, 256, 0, stream>>>(gacc, gtot, cntI);

    // layer 1: fp16 in -> fp16 intermediate out
    k_gemm<true><<<400, 256, 0, stream>>>(bufX16, (const float*)d_in[5], disv, bufG, N);
    k_agg<true><<<aggGrid, 256, 0, stream>>>(pairs2, noffs, bufG, disv,
                                             (const float*)d_in[6], batch, bufX16,
                                             gacc, N);
    k_pool<<<(GG * 2 * DD + 255) / 256, 256, 0, stream>>>(gacc, gtot, cntI);

    // layer 2: fp16 in -> f32 final out
    k_gemm<true><<<400, 256, 0, stream>>>(bufX16, (const float*)d_in[7], disv, bufG, N);
    k_agg<false><<<aggGrid, 256, 0, stream>>>(pairs2, noffs, bufG, disv,
                                              (const float*)d_in[8], batch, d_out,
                                              gacc, N);
    k_pool<<<(GG * 2 * DD + 255) / 256, 256, 0, stream>>>(gacc, gtot, cntI);

    k_copy<<<(GG * 2 * DD + 255) / 256, 256, 0, stream>>>(gtot, (float*)d_out + nd,
                                                          GG * 2 * DD);
}

// Round 14
// 313.493 us; speedup vs baseline: 1.5882x; 1.5882x over previous
//
#include <hip/hip_runtime.h>
#include <hip/hip_fp16.h>

#define DD 64     // feature dim
#define GG 64     // graphs per batch
#define CHUNK 16  // nodes per wave-chunk in k_agg
#define PBITS 9   // 512 nodes per coarse partition
#define PSZ 512
#define EPB 8192  // edges per histogram/sort block

typedef _Float16 half8 __attribute__((ext_vector_type(8)));
typedef float floatx4 __attribute__((ext_vector_type(4)));

// ---------------- per-block partition histogram (no global atomics) ----------
__global__ __launch_bounds__(512) void k_hist(const int* __restrict__ dst, int E,
                                              int* __restrict__ bcnt) {
    __shared__ int h[256];
    int t = threadIdx.x;
    if (t < 256) h[t] = 0;
    __syncthreads();
    int base = blockIdx.x * EPB;
    int n = min(EPB, E - base);
    for (int k = 0; k < EPB / 512; ++k) {
        int s = t + k * 512;
        if (s < n) atomicAdd(&h[dst[base + s] >> PBITS], 1);
    }
    __syncthreads();
    if (t < 256) bcnt[blockIdx.x * 256 + t] = h[t];
}

// ---------------- scan: bcnt -> per-(block,partition) bases; poffs ----------
__global__ __launch_bounds__(256) void k_scanB(int* __restrict__ bcnt, int nb,
                                               int* __restrict__ poffs,
                                               int* __restrict__ noffs,
                                               int N, int E) {
    __shared__ int sh[256];
    int t = threadIdx.x;
    int run = 0;
    for (int blk = 0; blk < nb; ++blk) {
        int v = bcnt[blk * 256 + t];
        bcnt[blk * 256 + t] = run;
        run += v;
    }
    int tot = run;
    sh[t] = tot;
    __syncthreads();
    for (int off = 1; off < 256; off <<= 1) {
        int u = (t >= off) ? sh[t - off] : 0;
        __syncthreads();
        sh[t] += u;
        __syncthreads();
    }
    int excl = sh[t] - tot;
    poffs[t] = excl;
    if (t == 0) {
        poffs[256] = E;
        noffs[N] = E;
    }
    for (int blk = 0; blk < nb; ++blk)
        bcnt[blk * 256 + t] += excl;
}

// ---------------- nodes-per-graph counts ----------------
__global__ __launch_bounds__(256) void k_count_batch(const int* __restrict__ batch, int N,
                                                     int* __restrict__ cntI) {
    __shared__ int h[GG];
    if (threadIdx.x < GG) h[threadIdx.x] = 0;
    __syncthreads();
    int i = blockIdx.x * 256 + threadIdx.x;
    if (i < N) atomicAdd(&h[batch[i]], 1);
    __syncthreads();
    if (threadIdx.x < GG) {
        int v = h[threadIdx.x];
        if (v) atomicAdd(&cntI[threadIdx.x], v);
    }
}

// ---------------- coarse sorted scatter (LDS counting sort per 8192 edges) ----
// word = src (17b) | (dst & 511) << 17 ; flush bases from bcnt (deterministic)
__global__ __launch_bounds__(512) void k_part1(const int* __restrict__ src,
                                               const int* __restrict__ dst, int E,
                                               const int* __restrict__ bcnt,
                                               unsigned* __restrict__ pairs1) {
    __shared__ unsigned stage[EPB];
    __shared__ unsigned char sbin[EPB];
    __shared__ int hist[256], binS[256], cur[256], gbase[256];
    int t = threadIdx.x;
    int base = blockIdx.x * EPB;
    int n = min(EPB, E - base);

    if (t < 256) {
        hist[t] = 0;
        gbase[t] = bcnt[blockIdx.x * 256 + t];
    }
    __syncthreads();
    for (int k = 0; k < EPB / 512; ++k) {
        int s = t + k * 512;
        if (s < n) atomicAdd(&hist[dst[base + s] >> PBITS], 1);
    }
    __syncthreads();
    int cnt = (t < 256) ? hist[t] : 0;
    for (int off = 1; off < 256; off <<= 1) {
        int v = 0;
        if (t >= off && t < 256) v = hist[t - off];
        __syncthreads();
        if (t < 256) hist[t] += v;
        __syncthreads();
    }
    if (t < 256) {
        int excl = hist[t] - cnt;
        binS[t] = excl;
        cur[t]  = excl;
    }
    __syncthreads();
    for (int k = 0; k < EPB / 512; ++k) {
        int s = t + k * 512;
        if (s < n) {
            int d = dst[base + s];
            int p = d >> PBITS;
            unsigned w = (unsigned)src[base + s] | ((unsigned)(d & (PSZ - 1)) << 17);
            int r = atomicAdd(&cur[p], 1);
            stage[r] = w;
            sbin[r]  = (unsigned char)p;
        }
    }
    __syncthreads();
    for (int k = 0; k < EPB / 512; ++k) {
        int s = t + k * 512;
        if (s < n) {
            int p = sbin[s];
            pairs1[gbase[p] + (s - binS[p])] = stage[s];
        }
    }
}

// ---------------- refine: full per-node sort within partition; emit noffs+dis -
__global__ __launch_bounds__(256) void k_part2(const unsigned* __restrict__ pairs1,
                                               const int* __restrict__ poffs,
                                               int* __restrict__ pairs2,
                                               int* __restrict__ noffs,
                                               float* __restrict__ disv, int N) {
    int p  = blockIdx.x;
    int pb = poffs[p], pe = poffs[p + 1];
    int len = pe - pb;
    __shared__ int h[PSZ];
    __shared__ int sc[256];
    int t = threadIdx.x;
    h[t] = 0;
    h[t + 256] = 0;
    __syncthreads();
    for (int s = t; s < len; s += 256)
        atomicAdd(&h[(pairs1[pb + s] >> 17) & (PSZ - 1)], 1);
    __syncthreads();
    int a  = h[2 * t];
    int b2 = h[2 * t + 1];
    sc[t] = a + b2;
    __syncthreads();
    for (int off = 1; off < 256; off <<= 1) {
        int u = (t >= off) ? sc[t - off] : 0;
        __syncthreads();
        sc[t] += u;
        __syncthreads();
    }
    int ex = sc[t] - (a + b2);
    int n0 = p * PSZ + 2 * t;
    if (n0 < N) {
        noffs[n0] = pb + ex;
        disv[n0]  = rsqrtf((float)(a + 1));
    }
    if (n0 + 1 < N) {
        noffs[n0 + 1] = pb + ex + a;
        disv[n0 + 1]  = rsqrtf((float)(b2 + 1));
    }
    __syncthreads();
    h[2 * t]     = ex;
    h[2 * t + 1] = ex + a;
    __syncthreads();
    for (int s = t; s < len; s += 256) {
        unsigned w = pairs1[pb + s];
        int r = atomicAdd(&h[(w >> 17) & (PSZ - 1)], 1);
        pairs2[pb + r] = (int)(w & 0x1FFFFu);
    }
}

// ---------------- g = fp16((x @ W) * dis[row])  — MFMA ----------------
template <bool FP16IN>
__global__ __launch_bounds__(256) void k_gemm(const void* __restrict__ xv,
                                              const float* __restrict__ W,
                                              const float* __restrict__ disv,
                                              __half* __restrict__ g, int N) {
    int lane = threadIdx.x & 63;
    int wave = (blockIdx.x * 256 + threadIdx.x) >> 6;
    int nw   = (gridDim.x * 256) >> 6;
    int col  = lane & 15;
    int krow = (lane >> 4) * 8;

    half8 bf[2][4];
#pragma unroll
    for (int s = 0; s < 2; ++s)
#pragma unroll
        for (int n = 0; n < 4; ++n)
#pragma unroll
            for (int e = 0; e < 8; ++e)
                bf[s][n][e] = (_Float16)W[(size_t)(krow + e + s * 32) * DD + n * 16 + col];

    int nch = (N + 15) >> 4;
    for (int c = wave; c < nch; c += nw) {
        int base = c * 16;
        int arow = min(base + (lane & 15), N - 1);
        half8 af[2];
        if constexpr (FP16IN) {
            const __half* xr = (const __half*)xv + (size_t)arow * DD + krow;
#pragma unroll
            for (int s = 0; s < 2; ++s)
                af[s] = *(const half8*)(xr + s * 32);
        } else {
            const float* xr = (const float*)xv + (size_t)arow * DD + krow;
#pragma unroll
            for (int s = 0; s < 2; ++s) {
                float4 lo = *(const float4*)(xr + s * 32);
                float4 hi = *(const float4*)(xr + s * 32 + 4);
                af[s][0] = (_Float16)lo.x; af[s][1] = (_Float16)lo.y;
                af[s][2] = (_Float16)lo.z; af[s][3] = (_Float16)lo.w;
                af[s][4] = (_Float16)hi.x; af[s][5] = (_Float16)hi.y;
                af[s][6] = (_Float16)hi.z; af[s][7] = (_Float16)hi.w;
            }
        }
        floatx4 acc[4] = {{0.f, 0.f, 0.f, 0.f}, {0.f, 0.f, 0.f, 0.f},
                          {0.f, 0.f, 0.f, 0.f}, {0.f, 0.f, 0.f, 0.f}};
#pragma unroll
        for (int s = 0; s < 2; ++s)
#pragma unroll
            for (int n = 0; n < 4; ++n)
                acc[n] = __builtin_amdgcn_mfma_f32_16x16x32_f16(af[s], bf[s][n],
                                                                acc[n], 0, 0, 0);
#pragma unroll
        for (int j = 0; j < 4; ++j) {
            int rr = base + (lane >> 4) * 4 + j;
            if (rr < N) {
                float dv = disv[rr];
#pragma unroll
                for (int n = 0; n < 4; ++n)
                    g[(size_t)rr * DD + n * 16 + col] = __float2half(acc[n][j] * dv);
            }
        }
    }
}

// ---------------- fused aggregate + finalize + pooling (register acc) --------
// Round-12 structure (CHUNK=16, 16-lane x uint2 groups, pk prefetch) with ONE
// change: issue depth 2 -> 4. Guard-free quad steps cover 16 edges; the
// remainder is ONE masked quad step (clamped indices, fma-masked adds), so
// mean-degree nodes need a single gather round.
template <bool FP16OUT>
__global__ __launch_bounds__(256) void k_agg(const int* __restrict__ pairs2,
                                             const int* __restrict__ noffs,
                                             const __half* __restrict__ g,
                                             const float* __restrict__ disv,
                                             const float* __restrict__ bbias,
                                             const int* __restrict__ batch,
                                             void* __restrict__ xoutv,
                                             float* __restrict__ gacc, int N) {
    int lane = threadIdx.x & 63;
    int g4   = lane >> 4;
    int l16  = lane & 15;
    int wave = (blockIdx.x * 256 + threadIdx.x) >> 6;
    int nw   = (gridDim.x * 256) >> 6;
    int NB   = (N + CHUNK - 1) / CHUNK;
    float4 bj = *(const float4*)&bbias[4 * l16];
    const char* gb = (const char*)g;
    for (int bu = wave; bu < NB; bu += nw) {
        int nbase = bu * CHUNK;
        int nend  = min(nbase + CHUNK, N);
        int nn    = nend - nbase;
        int nf  = noffs[nbase + min(lane, nn)];
        int bch = batch[nbase + min(lane, nn - 1)];
        float4 vmax = {0.f, 0.f, 0.f, 0.f}, vsum = {0.f, 0.f, 0.f, 0.f};
        int curg = __shfl(bch, 0);
        // prologue: prefetch node 0's first edge-index block
        int ps0  = __shfl(nf, 0);
        int pcnt = __shfl(nf, 1) - ps0;
        int pkpre = (lane < min(pcnt, 64)) ? pairs2[ps0 + lane] : 0;
        for (int i = 0; i < nn; ++i) {
            int pk   = pkpre;
            int s0   = ps0;
            int cnt  = pcnt;
            if (i + 1 < nn) {   // prefetch next node's block (independent of gathers)
                int ns0  = __shfl(nf, i + 1);
                int ncnt = __shfl(nf, i + 2) - ns0;
                pkpre = (lane < min(ncnt, 64)) ? pairs2[ns0 + lane] : 0;
                ps0 = ns0;
                pcnt = ncnt;
            }
            float4 acc = {0.f, 0.f, 0.f, 0.f};
            if (g4 == 0) {   // self-loop row
                uint2 rv = *(const uint2*)(gb + ((size_t)(nbase + i) * 128 + l16 * 8));
                float2 f0 = __half22float2(*(const __half2*)&rv.x);
                float2 f1 = __half22float2(*(const __half2*)&rv.y);
                acc.x = f0.x; acc.y = f0.y; acc.z = f1.x; acc.w = f1.y;
            }
            int kk0 = min(cnt, 64);
            int j = 0;
            for (; j + 16 <= kk0; j += 16) {   // guard-free quad-issue: 16 edges/step
                int sA = __shfl(pk, j + g4);
                int sB = __shfl(pk, j + 4 + g4);
                int sC = __shfl(pk, j + 8 + g4);
                int sD = __shfl(pk, j + 12 + g4);
                uint2 rA = *(const uint2*)(gb + ((size_t)sA * 128 + l16 * 8));
                uint2 rB = *(const uint2*)(gb + ((size_t)sB * 128 + l16 * 8));
                uint2 rC = *(const uint2*)(gb + ((size_t)sC * 128 + l16 * 8));
                uint2 rD = *(const uint2*)(gb + ((size_t)sD * 128 + l16 * 8));
                float2 a0 = __half22float2(*(const __half2*)&rA.x);
                float2 a1 = __half22float2(*(const __half2*)&rA.y);
                float2 b0 = __half22float2(*(const __half2*)&rB.x);
                float2 b1 = __half22float2(*(const __half2*)&rB.y);
                float2 c0 = __half22float2(*(const __half2*)&rC.x);
                float2 c1 = __half22float2(*(const __half2*)&rC.y);
                float2 d0 = __half22float2(*(const __half2*)&rD.x);
                float2 d1 = __half22float2(*(const __half2*)&rD.y);
                acc.x += (a0.x + b0.x) + (c0.x + d0.x);
                acc.y += (a0.y + b0.y) + (c0.y + d0.y);
                acc.z += (a1.x + b1.x) + (c1.x + d1.x);
                acc.w += (a1.y + b1.y) + (c1.y + d1.y);
            }
            if (j < kk0) {                     // ONE masked quad step (<=15 edges)
                int i0 = j + g4, i1 = j + 4 + g4, i2 = j + 8 + g4, i3 = j + 12 + g4;
                int sA = __shfl(pk, min(i0, kk0 - 1));
                int sB = __shfl(pk, min(i1, kk0 - 1));
                int sC = __shfl(pk, min(i2, kk0 - 1));
                int sD = __shfl(pk, min(i3, kk0 - 1));
                uint2 rA = *(const uint2*)(gb + ((size_t)sA * 128 + l16 * 8));
                uint2 rB = *(const uint2*)(gb + ((size_t)sB * 128 + l16 * 8));
                uint2 rC = *(const uint2*)(gb + ((size_t)sC * 128 + l16 * 8));
                uint2 rD = *(const uint2*)(gb + ((size_t)sD * 128 + l16 * 8));
                float mA = (i0 < kk0) ? 1.f : 0.f;
                float mB = (i1 < kk0) ? 1.f : 0.f;
                float mC = (i2 < kk0) ? 1.f : 0.f;
                float mD = (i3 < kk0) ? 1.f : 0.f;
                float2 a0 = __half22float2(*(const __half2*)&rA.x);
                float2 a1 = __half22float2(*(const __half2*)&rA.y);
                float2 b0 = __half22float2(*(const __half2*)&rB.x);
                float2 b1 = __half22float2(*(const __half2*)&rB.y);
                float2 c0 = __half22float2(*(const __half2*)&rC.x);
                float2 c1 = __half22float2(*(const __half2*)&rC.y);
                float2 d0 = __half22float2(*(const __half2*)&rD.x);
                float2 d1 = __half22float2(*(const __half2*)&rD.y);
                acc.x = fmaf(mA, a0.x, fmaf(mB, b0.x, fmaf(mC, c0.x, fmaf(mD, d0.x, acc.x))));
                acc.y = fmaf(mA, a0.y, fmaf(mB, b0.y, fmaf(mC, c0.y, fmaf(mD, d0.y, acc.y))));
                acc.z = fmaf(mA, a1.x, fmaf(mB, b1.x, fmaf(mC, c1.x, fmaf(mD, d1.x, acc.z))));
                acc.w = fmaf(mA, a1.y, fmaf(mB, b1.y, fmaf(mC, c1.y, fmaf(mD, d1.y, acc.w))));
            }
            // rare tail: degree > 64
            for (int k = 64; k < cnt; k += 64) {
                int kk = min(cnt - k, 64);
                int pkx = (lane < kk) ? pairs2[s0 + k + lane] : 0;
                for (int jj = 0; jj < kk; jj += 4) {
                    int idx  = jj + g4;
                    int sidx = __shfl(pkx, min(idx, kk - 1));
                    if (idx < kk) {
                        uint2 rv = *(const uint2*)(gb + ((size_t)sidx * 128 + l16 * 8));
                        float2 f0 = __half22float2(*(const __half2*)&rv.x);
                        float2 f1 = __half22float2(*(const __half2*)&rv.y);
                        acc.x += f0.x; acc.y += f0.y; acc.z += f1.x; acc.w += f1.y;
                    }
                }
            }
            acc.x += __shfl_xor(acc.x, 16);
            acc.y += __shfl_xor(acc.y, 16);
            acc.z += __shfl_xor(acc.z, 16);
            acc.w += __shfl_xor(acc.w, 16);
            acc.x += __shfl_xor(acc.x, 32);
            acc.y += __shfl_xor(acc.y, 32);
            acc.z += __shfl_xor(acc.z, 32);
            acc.w += __shfl_xor(acc.w, 32);
            float dv = disv[nbase + i];
            float4 v;
            v.x = fmaxf(fmaf(dv, acc.x, bj.x), 0.f);
            v.y = fmaxf(fmaf(dv, acc.y, bj.y), 0.f);
            v.z = fmaxf(fmaf(dv, acc.z, bj.z), 0.f);
            v.w = fmaxf(fmaf(dv, acc.w, bj.w), 0.f);
            if (g4 == 0) {
                if constexpr (FP16OUT) {
                    __half2 h0 = __float22half2_rn({v.x, v.y});
                    __half2 h1 = __float22half2_rn({v.z, v.w});
                    uint2 pkd = {*(unsigned*)&h0, *(unsigned*)&h1};
                    *(uint2*)((__half*)xoutv + (size_t)(nbase + i) * DD + 4 * l16) = pkd;
                } else {
                    *(float4*)((float*)xoutv + (size_t)(nbase + i) * DD + 4 * l16) = v;
                }
            }
            int gid = __shfl(bch, i);
            if (gid != curg) {
                if (g4 == 0) {
                    atomicMax((unsigned*)&gacc[curg * 128 + 4 * l16 + 0], __float_as_uint(vmax.x));
                    atomicMax((unsigned*)&gacc[curg * 128 + 4 * l16 + 1], __float_as_uint(vmax.y));
                    atomicMax((unsigned*)&gacc[curg * 128 + 4 * l16 + 2], __float_as_uint(vmax.z));
                    atomicMax((unsigned*)&gacc[curg * 128 + 4 * l16 + 3], __float_as_uint(vmax.w));
                    atomicAdd(&gacc[curg * 128 + 64 + 4 * l16 + 0], vsum.x);
                    atomicAdd(&gacc[curg * 128 + 64 + 4 * l16 + 1], vsum.y);
                    atomicAdd(&gacc[curg * 128 + 64 + 4 * l16 + 2], vsum.z);
                    atomicAdd(&gacc[curg * 128 + 64 + 4 * l16 + 3], vsum.w);
                }
                vmax = {0.f, 0.f, 0.f, 0.f};
                vsum = {0.f, 0.f, 0.f, 0.f};
                curg = gid;
            }
            vmax.x = fmaxf(vmax.x, v.x);
            vmax.y = fmaxf(vmax.y, v.y);
            vmax.z = fmaxf(vmax.z, v.z);
            vmax.w = fmaxf(vmax.w, v.w);
            vsum.x += v.x; vsum.y += v.y; vsum.z += v.z; vsum.w += v.w;
        }
        if (g4 == 0) {
            atomicMax((unsigned*)&gacc[curg * 128 + 4 * l16 + 0], __float_as_uint(vmax.x));
            atomicMax((unsigned*)&gacc[curg * 128 + 4 * l16 + 1], __float_as_uint(vmax.y));
            atomicMax((unsigned*)&gacc[curg * 128 + 4 * l16 + 2], __float_as_uint(vmax.z));
            atomicMax((unsigned*)&gacc[curg * 128 + 4 * l16 + 3], __float_as_uint(vmax.w));
            atomicAdd(&gacc[curg * 128 + 64 + 4 * l16 + 0], vsum.x);
            atomicAdd(&gacc[curg * 128 + 64 + 4 * l16 + 1], vsum.y);
            atomicAdd(&gacc[curg * 128 + 64 + 4 * l16 + 2], vsum.z);
            atomicAdd(&gacc[curg * 128 + 64 + 4 * l16 + 3], vsum.w);
        }
    }
}

// ---------------- fold per-layer pool into running total; clear gacc ---------
__global__ __launch_bounds__(256) void k_pool(float* __restrict__ gacc,
                                              float* __restrict__ gtot,
                                              const int* __restrict__ cntI) {
    int i = blockIdx.x * 256 + threadIdx.x;
    if (i < GG * 2 * DD) {
        int gidx = i >> 7;
        int j    = i & 127;
        float v  = gacc[i];
        if (j >= DD) v = v / (float)cntI[gidx];
        gtot[i] += v;
        gacc[i] = 0.f;
    }
}

__global__ __launch_bounds__(256) void k_copy(const float* __restrict__ srcp,
                                              float* __restrict__ dstp, int n) {
    int i = blockIdx.x * 256 + threadIdx.x;
    if (i < n) dstp[i] = srcp[i];
}

extern "C" void kernel_launch(void* const* d_in, const int* in_sizes, int n_in,
                              void* d_out, int out_size, void* d_ws, size_t ws_size,
                              hipStream_t stream) {
    const float* x     = (const float*)d_in[0];
    const int*   ei    = (const int*)d_in[1];
    const int*   batch = (const int*)d_in[2];

    int N = in_sizes[0] / DD;
    int E = in_sizes[1] / 2;
    const int* src = ei;
    const int* dst = ei + E;

    size_t nd  = (size_t)N * DD;
    int NPART  = (N + PSZ - 1) >> PBITS;
    int NB     = (N + CHUNK - 1) / CHUNK;
    int nb     = (E + EPB - 1) / EPB;

    float*    ws     = (float*)d_ws;
    float*    bufX   = ws;                            // N*DD (f32-sized; fp16 used)
    __half*   bufX16 = (__half*)bufX;
    __half*   bufG   = (__half*)(ws + nd);            // N*DD fp16
    float*    disv   = ws + nd + nd / 2;              // N
    float*    gacc   = disv + N;                      // GG*2*DD
    float*    gtot   = gacc + GG * 2 * DD;            // GG*2*DD
    int*      cntI   = (int*)(gtot + GG * 2 * DD);    // GG
    int*      poffs  = cntI + GG;                     // 257
    int*      noffs  = poffs + 257;                   // N+1
    int*      bcnt   = noffs + N + 1;                 // nb*256
    unsigned* pairs1 = (unsigned*)(bcnt + nb * 256);  // E
    int*      pairs2 = (int*)(pairs1 + E);            // E

    hipMemsetAsync(gacc, 0, (size_t)GG * 2 * DD * sizeof(float), stream);
    hipMemsetAsync(gtot, 0, (size_t)GG * 2 * DD * sizeof(float), stream);
    hipMemsetAsync(cntI, 0, (size_t)GG * sizeof(int), stream);

    k_hist<<<nb, 512, 0, stream>>>(dst, E, bcnt);
    k_scanB<<<1, 256, 0, stream>>>(bcnt, nb, poffs, noffs, N, E);
    k_count_batch<<<(N + 255) / 256, 256, 0, stream>>>(batch, N, cntI);
    k_part1<<<nb, 512, 0, stream>>>(src, dst, E, bcnt, pairs1);
    k_part2<<<NPART, 256, 0, stream>>>(pairs1, poffs, pairs2, noffs, disv, N);

    int aggGrid = (NB + 3) / 4;

    // layer 0: f32 in -> fp16 intermediate out
    k_gemm<false><<<400, 256, 0, stream>>>(x, (const float*)d_in[3], disv, bufG, N);
    k_agg<true><<<aggGrid, 256, 0, stream>>>(pairs2, noffs, bufG, disv,
                                             (const float*)d_in[4], batch, bufX16,
                                             gacc, N);
    k_pool<<<(GG * 2 * DD + 255) / 256, 256, 0, stream>>>(gacc, gtot, cntI);

    // layer 1: fp16 in -> fp16 intermediate out
    k_gemm<true><<<400, 256, 0, stream>>>(bufX16, (const float*)d_in[5], disv, bufG, N);
    k_agg<true><<<aggGrid, 256, 0, stream>>>(pairs2, noffs, bufG, disv,
                                             (const float*)d_in[6], batch, bufX16,
                                             gacc, N);
    k_pool<<<(GG * 2 * DD + 255) / 256, 256, 0, stream>>>(gacc, gtot, cntI);

    // layer 2: fp16 in -> f32 final out
    k_gemm<true><<<400, 256, 0, stream>>>(bufX16, (const float*)d_in[7], disv, bufG, N);
    k_agg<false><<<aggGrid, 256, 0, stream>>>(pairs2, noffs, bufG, disv,
                                              (const float*)d_in[8], batch, d_out,
                                              gacc, N);
    k_pool<<<(GG * 2 * DD + 255) / 256, 256, 0, stream>>>(gacc, gtot, cntI);

    k_copy<<<(GG * 2 * DD + 255) / 256, 256, 0, stream>>>(gtot, (float*)d_out + nd,
                                                          GG * 2 * DD);
}

// Round 15
// 290.812 us; speedup vs baseline: 1.7120x; 1.0780x over previous
//
#include <hip/hip_runtime.h>
#include <hip/hip_fp16.h>

#define DD 64     // feature dim
#define GG 64     // graphs per batch
#define CHUNK 16  // nodes per wave-chunk in k_agg
#define PBITS 9   // 512 nodes per coarse partition
#define PSZ 512
#define EPB 8192  // edges per histogram/sort block

typedef _Float16 half8 __attribute__((ext_vector_type(8)));
typedef float floatx4 __attribute__((ext_vector_type(4)));

// ---------------- per-block partition histogram (no global atomics) ----------
__global__ __launch_bounds__(512) void k_hist(const int* __restrict__ dst, int E,
                                              int* __restrict__ bcnt) {
    __shared__ int h[256];
    int t = threadIdx.x;
    if (t < 256) h[t] = 0;
    __syncthreads();
    int base = blockIdx.x * EPB;
    int n = min(EPB, E - base);
    for (int k = 0; k < EPB / 512; ++k) {
        int s = t + k * 512;
        if (s < n) atomicAdd(&h[dst[base + s] >> PBITS], 1);
    }
    __syncthreads();
    if (t < 256) bcnt[blockIdx.x * 256 + t] = h[t];
}

// ---------------- scan: bcnt -> per-(block,partition) bases; poffs ----------
__global__ __launch_bounds__(256) void k_scanB(int* __restrict__ bcnt, int nb,
                                               int* __restrict__ poffs,
                                               int* __restrict__ noffs,
                                               int N, int E) {
    __shared__ int sh[256];
    int t = threadIdx.x;
    int run = 0;
    for (int blk = 0; blk < nb; ++blk) {
        int v = bcnt[blk * 256 + t];
        bcnt[blk * 256 + t] = run;
        run += v;
    }
    int tot = run;
    sh[t] = tot;
    __syncthreads();
    for (int off = 1; off < 256; off <<= 1) {
        int u = (t >= off) ? sh[t - off] : 0;
        __syncthreads();
        sh[t] += u;
        __syncthreads();
    }
    int excl = sh[t] - tot;
    poffs[t] = excl;
    if (t == 0) {
        poffs[256] = E;
        noffs[N] = E;
    }
    for (int blk = 0; blk < nb; ++blk)
        bcnt[blk * 256 + t] += excl;
}

// ---------------- nodes-per-graph counts ----------------
__global__ __launch_bounds__(256) void k_count_batch(const int* __restrict__ batch, int N,
                                                     int* __restrict__ cntI) {
    __shared__ int h[GG];
    if (threadIdx.x < GG) h[threadIdx.x] = 0;
    __syncthreads();
    int i = blockIdx.x * 256 + threadIdx.x;
    if (i < N) atomicAdd(&h[batch[i]], 1);
    __syncthreads();
    if (threadIdx.x < GG) {
        int v = h[threadIdx.x];
        if (v) atomicAdd(&cntI[threadIdx.x], v);
    }
}

// ---------------- coarse sorted scatter (LDS counting sort per 8192 edges) ----
// word = src (17b) | (dst & 511) << 17 ; flush bases from bcnt (deterministic)
__global__ __launch_bounds__(512) void k_part1(const int* __restrict__ src,
                                               const int* __restrict__ dst, int E,
                                               const int* __restrict__ bcnt,
                                               unsigned* __restrict__ pairs1) {
    __shared__ unsigned stage[EPB];
    __shared__ unsigned char sbin[EPB];
    __shared__ int hist[256], binS[256], cur[256], gbase[256];
    int t = threadIdx.x;
    int base = blockIdx.x * EPB;
    int n = min(EPB, E - base);

    if (t < 256) {
        hist[t] = 0;
        gbase[t] = bcnt[blockIdx.x * 256 + t];
    }
    __syncthreads();
    for (int k = 0; k < EPB / 512; ++k) {
        int s = t + k * 512;
        if (s < n) atomicAdd(&hist[dst[base + s] >> PBITS], 1);
    }
    __syncthreads();
    int cnt = (t < 256) ? hist[t] : 0;
    for (int off = 1; off < 256; off <<= 1) {
        int v = 0;
        if (t >= off && t < 256) v = hist[t - off];
        __syncthreads();
        if (t < 256) hist[t] += v;
        __syncthreads();
    }
    if (t < 256) {
        int excl = hist[t] - cnt;
        binS[t] = excl;
        cur[t]  = excl;
    }
    __syncthreads();
    for (int k = 0; k < EPB / 512; ++k) {
        int s = t + k * 512;
        if (s < n) {
            int d = dst[base + s];
            int p = d >> PBITS;
            unsigned w = (unsigned)src[base + s] | ((unsigned)(d & (PSZ - 1)) << 17);
            int r = atomicAdd(&cur[p], 1);
            stage[r] = w;
            sbin[r]  = (unsigned char)p;
        }
    }
    __syncthreads();
    for (int k = 0; k < EPB / 512; ++k) {
        int s = t + k * 512;
        if (s < n) {
            int p = sbin[s];
            pairs1[gbase[p] + (s - binS[p])] = stage[s];
        }
    }
}

// ---------------- refine: full per-node sort within partition; emit noffs+dis -
__global__ __launch_bounds__(256) void k_part2(const unsigned* __restrict__ pairs1,
                                               const int* __restrict__ poffs,
                                               int* __restrict__ pairs2,
                                               int* __restrict__ noffs,
                                               float* __restrict__ disv, int N) {
    int p  = blockIdx.x;
    int pb = poffs[p], pe = poffs[p + 1];
    int len = pe - pb;
    __shared__ int h[PSZ];
    __shared__ int sc[256];
    int t = threadIdx.x;
    h[t] = 0;
    h[t + 256] = 0;
    __syncthreads();
    for (int s = t; s < len; s += 256)
        atomicAdd(&h[(pairs1[pb + s] >> 17) & (PSZ - 1)], 1);
    __syncthreads();
    int a  = h[2 * t];
    int b2 = h[2 * t + 1];
    sc[t] = a + b2;
    __syncthreads();
    for (int off = 1; off < 256; off <<= 1) {
        int u = (t >= off) ? sc[t - off] : 0;
        __syncthreads();
        sc[t] += u;
        __syncthreads();
    }
    int ex = sc[t] - (a + b2);
    int n0 = p * PSZ + 2 * t;
    if (n0 < N) {
        noffs[n0] = pb + ex;
        disv[n0]  = rsqrtf((float)(a + 1));
    }
    if (n0 + 1 < N) {
        noffs[n0 + 1] = pb + ex + a;
        disv[n0 + 1]  = rsqrtf((float)(b2 + 1));
    }
    __syncthreads();
    h[2 * t]     = ex;
    h[2 * t + 1] = ex + a;
    __syncthreads();
    for (int s = t; s < len; s += 256) {
        unsigned w = pairs1[pb + s];
        int r = atomicAdd(&h[(w >> 17) & (PSZ - 1)], 1);
        pairs2[pb + r] = (int)(w & 0x1FFFFu);
    }
}

// ---------------- g = fp16((x @ W) * dis[row])  — MFMA ----------------
template <bool FP16IN>
__global__ __launch_bounds__(256) void k_gemm(const void* __restrict__ xv,
                                              const float* __restrict__ W,
                                              const float* __restrict__ disv,
                                              __half* __restrict__ g, int N) {
    int lane = threadIdx.x & 63;
    int wave = (blockIdx.x * 256 + threadIdx.x) >> 6;
    int nw   = (gridDim.x * 256) >> 6;
    int col  = lane & 15;
    int krow = (lane >> 4) * 8;

    half8 bf[2][4];
#pragma unroll
    for (int s = 0; s < 2; ++s)
#pragma unroll
        for (int n = 0; n < 4; ++n)
#pragma unroll
            for (int e = 0; e < 8; ++e)
                bf[s][n][e] = (_Float16)W[(size_t)(krow + e + s * 32) * DD + n * 16 + col];

    int nch = (N + 15) >> 4;
    for (int c = wave; c < nch; c += nw) {
        int base = c * 16;
        int arow = min(base + (lane & 15), N - 1);
        half8 af[2];
        if constexpr (FP16IN) {
            const __half* xr = (const __half*)xv + (size_t)arow * DD + krow;
#pragma unroll
            for (int s = 0; s < 2; ++s)
                af[s] = *(const half8*)(xr + s * 32);
        } else {
            const float* xr = (const float*)xv + (size_t)arow * DD + krow;
#pragma unroll
            for (int s = 0; s < 2; ++s) {
                float4 lo = *(const float4*)(xr + s * 32);
                float4 hi = *(const float4*)(xr + s * 32 + 4);
                af[s][0] = (_Float16)lo.x; af[s][1] = (_Float16)lo.y;
                af[s][2] = (_Float16)lo.z; af[s][3] = (_Float16)lo.w;
                af[s][4] = (_Float16)hi.x; af[s][5] = (_Float16)hi.y;
                af[s][6] = (_Float16)hi.z; af[s][7] = (_Float16)hi.w;
            }
        }
        floatx4 acc[4] = {{0.f, 0.f, 0.f, 0.f}, {0.f, 0.f, 0.f, 0.f},
                          {0.f, 0.f, 0.f, 0.f}, {0.f, 0.f, 0.f, 0.f}};
#pragma unroll
        for (int s = 0; s < 2; ++s)
#pragma unroll
            for (int n = 0; n < 4; ++n)
                acc[n] = __builtin_amdgcn_mfma_f32_16x16x32_f16(af[s], bf[s][n],
                                                                acc[n], 0, 0, 0);
#pragma unroll
        for (int j = 0; j < 4; ++j) {
            int rr = base + (lane >> 4) * 4 + j;
            if (rr < N) {
                float dv = disv[rr];
#pragma unroll
                for (int n = 0; n < 4; ++n)
                    g[(size_t)rr * DD + n * 16 + col] = __float2half(acc[n][j] * dv);
            }
        }
    }
}

// ---------------- fused aggregate + finalize + pooling (register acc) --------
// r12 proven config: CHUNK=16, staged pk + guarded dual-load + cross-node
// pk prefetch. gacc is PER-LAYER (deferred pooling fold).
template <bool FP16OUT>
__global__ __launch_bounds__(256) void k_agg(const int* __restrict__ pairs2,
                                             const int* __restrict__ noffs,
                                             const __half* __restrict__ g,
                                             const float* __restrict__ disv,
                                             const float* __restrict__ bbias,
                                             const int* __restrict__ batch,
                                             void* __restrict__ xoutv,
                                             float* __restrict__ gacc, int N) {
    int lane = threadIdx.x & 63;
    int g4   = lane >> 4;
    int l16  = lane & 15;
    int wave = (blockIdx.x * 256 + threadIdx.x) >> 6;
    int nw   = (gridDim.x * 256) >> 6;
    int NB   = (N + CHUNK - 1) / CHUNK;
    float4 bj = *(const float4*)&bbias[4 * l16];
    const char* gb = (const char*)g;
    for (int bu = wave; bu < NB; bu += nw) {
        int nbase = bu * CHUNK;
        int nend  = min(nbase + CHUNK, N);
        int nn    = nend - nbase;
        int nf  = noffs[nbase + min(lane, nn)];
        int bch = batch[nbase + min(lane, nn - 1)];
        float4 vmax = {0.f, 0.f, 0.f, 0.f}, vsum = {0.f, 0.f, 0.f, 0.f};
        int curg = __shfl(bch, 0);
        // prologue: prefetch node 0's first edge-index block
        int ps0  = __shfl(nf, 0);
        int pcnt = __shfl(nf, 1) - ps0;
        int pkpre = (lane < min(pcnt, 64)) ? pairs2[ps0 + lane] : 0;
        for (int i = 0; i < nn; ++i) {
            int pk   = pkpre;
            int s0   = ps0;
            int cnt  = pcnt;
            if (i + 1 < nn) {   // prefetch next node's block (independent of gathers)
                int ns0  = __shfl(nf, i + 1);
                int ncnt = __shfl(nf, i + 2) - ns0;
                pkpre = (lane < min(ncnt, 64)) ? pairs2[ns0 + lane] : 0;
                ps0 = ns0;
                pcnt = ncnt;
            }
            float4 acc = {0.f, 0.f, 0.f, 0.f};
            if (g4 == 0) {   // self-loop row
                uint2 rv = *(const uint2*)(gb + ((size_t)(nbase + i) * 128 + l16 * 8));
                float2 f0 = __half22float2(*(const __half2*)&rv.x);
                float2 f1 = __half22float2(*(const __half2*)&rv.y);
                acc.x = f0.x; acc.y = f0.y; acc.z = f1.x; acc.w = f1.y;
            }
            int kk0 = min(cnt, 64);
            int j = 0;
            for (; j + 8 <= kk0; j += 8) {   // guard-free dual-issue path
                int sA = __shfl(pk, j + g4);
                int sB = __shfl(pk, j + 4 + g4);
                uint2 rA = *(const uint2*)(gb + ((size_t)sA * 128 + l16 * 8));
                uint2 rB = *(const uint2*)(gb + ((size_t)sB * 128 + l16 * 8));
                float2 a0 = __half22float2(*(const __half2*)&rA.x);
                float2 a1 = __half22float2(*(const __half2*)&rA.y);
                float2 b0 = __half22float2(*(const __half2*)&rB.x);
                float2 b1 = __half22float2(*(const __half2*)&rB.y);
                acc.x += a0.x + b0.x;
                acc.y += a0.y + b0.y;
                acc.z += a1.x + b1.x;
                acc.w += a1.y + b1.y;
            }
            for (; j < kk0; j += 4) {        // guarded remainder
                int idx  = j + g4;
                int sidx = __shfl(pk, idx);
                if (idx < kk0) {
                    uint2 rv = *(const uint2*)(gb + ((size_t)sidx * 128 + l16 * 8));
                    float2 f0 = __half22float2(*(const __half2*)&rv.x);
                    float2 f1 = __half22float2(*(const __half2*)&rv.y);
                    acc.x += f0.x; acc.y += f0.y; acc.z += f1.x; acc.w += f1.y;
                }
            }
            // rare tail: degree > 64
            for (int k = 64; k < cnt; k += 64) {
                int kk = min(cnt - k, 64);
                int pkx = (lane < kk) ? pairs2[s0 + k + lane] : 0;
                for (int jj = 0; jj < kk; jj += 4) {
                    int idx  = jj + g4;
                    int sidx = __shfl(pkx, idx);
                    if (idx < kk) {
                        uint2 rv = *(const uint2*)(gb + ((size_t)sidx * 128 + l16 * 8));
                        float2 f0 = __half22float2(*(const __half2*)&rv.x);
                        float2 f1 = __half22float2(*(const __half2*)&rv.y);
                        acc.x += f0.x; acc.y += f0.y; acc.z += f1.x; acc.w += f1.y;
                    }
                }
            }
            acc.x += __shfl_xor(acc.x, 16);
            acc.y += __shfl_xor(acc.y, 16);
            acc.z += __shfl_xor(acc.z, 16);
            acc.w += __shfl_xor(acc.w, 16);
            acc.x += __shfl_xor(acc.x, 32);
            acc.y += __shfl_xor(acc.y, 32);
            acc.z += __shfl_xor(acc.z, 32);
            acc.w += __shfl_xor(acc.w, 32);
            float dv = disv[nbase + i];
            float4 v;
            v.x = fmaxf(fmaf(dv, acc.x, bj.x), 0.f);
            v.y = fmaxf(fmaf(dv, acc.y, bj.y), 0.f);
            v.z = fmaxf(fmaf(dv, acc.z, bj.z), 0.f);
            v.w = fmaxf(fmaf(dv, acc.w, bj.w), 0.f);
            if (g4 == 0) {
                if constexpr (FP16OUT) {
                    __half2 h0 = __float22half2_rn({v.x, v.y});
                    __half2 h1 = __float22half2_rn({v.z, v.w});
                    uint2 pkd = {*(unsigned*)&h0, *(unsigned*)&h1};
                    *(uint2*)((__half*)xoutv + (size_t)(nbase + i) * DD + 4 * l16) = pkd;
                } else {
                    *(float4*)((float*)xoutv + (size_t)(nbase + i) * DD + 4 * l16) = v;
                }
            }
            int gid = __shfl(bch, i);
            if (gid != curg) {
                if (g4 == 0) {
                    atomicMax((unsigned*)&gacc[curg * 128 + 4 * l16 + 0], __float_as_uint(vmax.x));
                    atomicMax((unsigned*)&gacc[curg * 128 + 4 * l16 + 1], __float_as_uint(vmax.y));
                    atomicMax((unsigned*)&gacc[curg * 128 + 4 * l16 + 2], __float_as_uint(vmax.z));
                    atomicMax((unsigned*)&gacc[curg * 128 + 4 * l16 + 3], __float_as_uint(vmax.w));
                    atomicAdd(&gacc[curg * 128 + 64 + 4 * l16 + 0], vsum.x);
                    atomicAdd(&gacc[curg * 128 + 64 + 4 * l16 + 1], vsum.y);
                    atomicAdd(&gacc[curg * 128 + 64 + 4 * l16 + 2], vsum.z);
                    atomicAdd(&gacc[curg * 128 + 64 + 4 * l16 + 3], vsum.w);
                }
                vmax = {0.f, 0.f, 0.f, 0.f};
                vsum = {0.f, 0.f, 0.f, 0.f};
                curg = gid;
            }
            vmax.x = fmaxf(vmax.x, v.x);
            vmax.y = fmaxf(vmax.y, v.y);
            vmax.z = fmaxf(vmax.z, v.z);
            vmax.w = fmaxf(vmax.w, v.w);
            vsum.x += v.x; vsum.y += v.y; vsum.z += v.z; vsum.w += v.w;
        }
        if (g4 == 0) {
            atomicMax((unsigned*)&gacc[curg * 128 + 4 * l16 + 0], __float_as_uint(vmax.x));
            atomicMax((unsigned*)&gacc[curg * 128 + 4 * l16 + 1], __float_as_uint(vmax.y));
            atomicMax((unsigned*)&gacc[curg * 128 + 4 * l16 + 2], __float_as_uint(vmax.z));
            atomicMax((unsigned*)&gacc[curg * 128 + 4 * l16 + 3], __float_as_uint(vmax.w));
            atomicAdd(&gacc[curg * 128 + 64 + 4 * l16 + 0], vsum.x);
            atomicAdd(&gacc[curg * 128 + 64 + 4 * l16 + 1], vsum.y);
            atomicAdd(&gacc[curg * 128 + 64 + 4 * l16 + 2], vsum.z);
            atomicAdd(&gacc[curg * 128 + 64 + 4 * l16 + 3], vsum.w);
        }
    }
}

// ---------------- final pooling fold: sum 3 per-layer gacc -> d_out graph part
__global__ __launch_bounds__(256) void k_poolF(const float* __restrict__ gacc,
                                               const int* __restrict__ cntI,
                                               float* __restrict__ outg) {
    int i = blockIdx.x * 256 + threadIdx.x;
    if (i < GG * 2 * DD) {
        int gidx = i >> 7;
        int j    = i & 127;
        float v = gacc[i] + gacc[GG * 2 * DD + i] + gacc[2 * GG * 2 * DD + i];
        if (j >= DD) v = v / (float)cntI[gidx];
        outg[i] = v;
    }
}

extern "C" void kernel_launch(void* const* d_in, const int* in_sizes, int n_in,
                              void* d_out, int out_size, void* d_ws, size_t ws_size,
                              hipStream_t stream) {
    const float* x     = (const float*)d_in[0];
    const int*   ei    = (const int*)d_in[1];
    const int*   batch = (const int*)d_in[2];

    int N = in_sizes[0] / DD;
    int E = in_sizes[1] / 2;
    const int* src = ei;
    const int* dst = ei + E;

    size_t nd  = (size_t)N * DD;
    int NPART  = (N + PSZ - 1) >> PBITS;
    int NB     = (N + CHUNK - 1) / CHUNK;
    int nb     = (E + EPB - 1) / EPB;

    float*    ws     = (float*)d_ws;
    float*    bufX   = ws;                            // N*DD (f32-sized; fp16 used)
    __half*   bufX16 = (__half*)bufX;
    __half*   bufG   = (__half*)(ws + nd);            // N*DD fp16
    float*    disv   = ws + nd + nd / 2;              // N
    float*    gacc   = disv + N;                      // 3 * GG*2*DD (per-layer)
    int*      cntI   = (int*)(gacc + 3 * GG * 2 * DD);  // GG
    int*      poffs  = cntI + GG;                     // 257
    int*      noffs  = poffs + 257;                   // N+1
    int*      bcnt   = noffs + N + 1;                 // nb*256
    unsigned* pairs1 = (unsigned*)(bcnt + nb * 256);  // E
    int*      pairs2 = (int*)(pairs1 + E);            // E

    hipMemsetAsync(gacc, 0, (size_t)3 * GG * 2 * DD * sizeof(float), stream);
    hipMemsetAsync(cntI, 0, (size_t)GG * sizeof(int), stream);

    k_hist<<<nb, 512, 0, stream>>>(dst, E, bcnt);
    k_scanB<<<1, 256, 0, stream>>>(bcnt, nb, poffs, noffs, N, E);
    k_count_batch<<<(N + 255) / 256, 256, 0, stream>>>(batch, N, cntI);
    k_part1<<<nb, 512, 0, stream>>>(src, dst, E, bcnt, pairs1);
    k_part2<<<NPART, 256, 0, stream>>>(pairs1, poffs, pairs2, noffs, disv, N);

    int aggGrid = (NB + 3) / 4;

    // layer 0: f32 in -> fp16 intermediate out
    k_gemm<false><<<400, 256, 0, stream>>>(x, (const float*)d_in[3], disv, bufG, N);
    k_agg<true><<<aggGrid, 256, 0, stream>>>(pairs2, noffs, bufG, disv,
                                             (const float*)d_in[4], batch, bufX16,
                                             gacc, N);
    // layer 1: fp16 in -> fp16 intermediate out
    k_gemm<true><<<400, 256, 0, stream>>>(bufX16, (const float*)d_in[5], disv, bufG, N);
    k_agg<true><<<aggGrid, 256, 0, stream>>>(pairs2, noffs, bufG, disv,
                                             (const float*)d_in[6], batch, bufX16,
                                             gacc + GG * 2 * DD, N);
    // layer 2: fp16 in -> f32 final out
    k_gemm<true><<<400, 256, 0, stream>>>(bufX16, (const float*)d_in[7], disv, bufG, N);
    k_agg<false><<<aggGrid, 256, 0, stream>>>(pairs2, noffs, bufG, disv,
                                              (const float*)d_in[8], batch, d_out,
                                              gacc + 2 * GG * 2 * DD, N);

    k_poolF<<<(GG * 2 * DD + 255) / 256, 256, 0, stream>>>(gacc, cntI,
                                                           (float*)d_out + nd);
}

// Round 16
// 244.523 us; speedup vs baseline: 2.0361x; 1.1893x over previous
//
#include <hip/hip_runtime.h>
#include <hip/hip_fp16.h>

#define DD 64     // feature dim
#define GG 64     // graphs per batch
#define CHUNK 16  // nodes per wave-chunk in k_agg
#define PBITS 9   // 512 nodes per coarse partition
#define PSZ 512
#define EPB 8192  // edges per histogram/sort block

typedef _Float16 half8 __attribute__((ext_vector_type(8)));
typedef float floatx4 __attribute__((ext_vector_type(4)));

// ---------------- per-block partition histogram (transposed store) ----------
__global__ __launch_bounds__(512) void k_hist(const int* __restrict__ dst, int E,
                                              int nb, int* __restrict__ bcnt) {
    __shared__ int h[256];
    int t = threadIdx.x;
    if (t < 256) h[t] = 0;
    __syncthreads();
    int base = blockIdx.x * EPB;
    int n = min(EPB, E - base);
    for (int k = 0; k < EPB / 512; ++k) {
        int s = t + k * 512;
        if (s < n) atomicAdd(&h[dst[base + s] >> PBITS], 1);
    }
    __syncthreads();
    if (t < 256) bcnt[t * nb + blockIdx.x] = h[t];   // [partition][block]
}

// ---------------- per-partition column scan (256 blocks, parallel) ----------
__global__ __launch_bounds__(256) void k_scanCol(const int* __restrict__ bcnt, int nb,
                                                 int* __restrict__ bpre,
                                                 int* __restrict__ ptot) {
    __shared__ int sh[256];
    int p = blockIdx.x, t = threadIdx.x;
    int v = (t < nb) ? bcnt[p * nb + t] : 0;
    sh[t] = v;
    __syncthreads();
    for (int off = 1; off < 256; off <<= 1) {
        int u = (t >= off) ? sh[t - off] : 0;
        __syncthreads();
        sh[t] += u;
        __syncthreads();
    }
    if (t < nb) bpre[p * nb + t] = sh[t] - v;
    if (t == 0) ptot[p] = sh[255];
}

// ---------------- tiny scan over partition totals -> poffs ----------
__global__ __launch_bounds__(256) void k_scanP(const int* __restrict__ ptot,
                                               int* __restrict__ poffs,
                                               int* __restrict__ noffs,
                                               int N, int E) {
    __shared__ int sh[256];
    int t = threadIdx.x;
    int v = ptot[t];
    sh[t] = v;
    __syncthreads();
    for (int off = 1; off < 256; off <<= 1) {
        int u = (t >= off) ? sh[t - off] : 0;
        __syncthreads();
        sh[t] += u;
        __syncthreads();
    }
    poffs[t] = sh[t] - v;
    if (t == 0) {
        poffs[256] = E;
        noffs[N] = E;
    }
}

// ---------------- nodes-per-graph counts ----------------
__global__ __launch_bounds__(256) void k_count_batch(const int* __restrict__ batch, int N,
                                                     int* __restrict__ cntI) {
    __shared__ int h[GG];
    if (threadIdx.x < GG) h[threadIdx.x] = 0;
    __syncthreads();
    int i = blockIdx.x * 256 + threadIdx.x;
    if (i < N) atomicAdd(&h[batch[i]], 1);
    __syncthreads();
    if (threadIdx.x < GG) {
        int v = h[threadIdx.x];
        if (v) atomicAdd(&cntI[threadIdx.x], v);
    }
}

// ---------------- coarse sorted scatter (histogram loaded, not recomputed) ---
// word = src (17b) | (dst & 511) << 17 ; gbase = poffs + bpre (deterministic)
__global__ __launch_bounds__(512) void k_part1(const int* __restrict__ src,
                                               const int* __restrict__ dst, int E,
                                               int nb,
                                               const int* __restrict__ bcnt,
                                               const int* __restrict__ bpre,
                                               const int* __restrict__ poffs,
                                               unsigned* __restrict__ pairs1) {
    __shared__ unsigned stage[EPB];
    __shared__ unsigned char sbin[EPB];
    __shared__ int hist[256], binS[256], cur[256], gbase[256];
    int t = threadIdx.x;
    int base = blockIdx.x * EPB;
    int n = min(EPB, E - base);

    if (t < 256) {
        int raw = bcnt[t * nb + blockIdx.x];
        hist[t]  = raw;
        gbase[t] = poffs[t] + bpre[t * nb + blockIdx.x];
    }
    __syncthreads();
    int cnt = (t < 256) ? hist[t] : 0;
    for (int off = 1; off < 256; off <<= 1) {
        int v = 0;
        if (t >= off && t < 256) v = hist[t - off];
        __syncthreads();
        if (t < 256) hist[t] += v;
        __syncthreads();
    }
    if (t < 256) {
        int excl = hist[t] - cnt;
        binS[t] = excl;
        cur[t]  = excl;
    }
    __syncthreads();
    for (int k = 0; k < EPB / 512; ++k) {
        int s = t + k * 512;
        if (s < n) {
            int d = dst[base + s];
            int p = d >> PBITS;
            unsigned w = (unsigned)src[base + s] | ((unsigned)(d & (PSZ - 1)) << 17);
            int r = atomicAdd(&cur[p], 1);
            stage[r] = w;
            sbin[r]  = (unsigned char)p;
        }
    }
    __syncthreads();
    for (int k = 0; k < EPB / 512; ++k) {
        int s = t + k * 512;
        if (s < n) {
            int p = sbin[s];
            pairs1[gbase[p] + (s - binS[p])] = stage[s];
        }
    }
}

// ---------------- refine: full per-node sort within partition; emit noffs+dis -
__global__ __launch_bounds__(256) void k_part2(const unsigned* __restrict__ pairs1,
                                               const int* __restrict__ poffs,
                                               int* __restrict__ pairs2,
                                               int* __restrict__ noffs,
                                               float* __restrict__ disv, int N) {
    int p  = blockIdx.x;
    int pb = poffs[p], pe = poffs[p + 1];
    int len = pe - pb;
    __shared__ int h[PSZ];
    __shared__ int sc[256];
    int t = threadIdx.x;
    h[t] = 0;
    h[t + 256] = 0;
    __syncthreads();
    for (int s = t; s < len; s += 256)
        atomicAdd(&h[(pairs1[pb + s] >> 17) & (PSZ - 1)], 1);
    __syncthreads();
    int a  = h[2 * t];
    int b2 = h[2 * t + 1];
    sc[t] = a + b2;
    __syncthreads();
    for (int off = 1; off < 256; off <<= 1) {
        int u = (t >= off) ? sc[t - off] : 0;
        __syncthreads();
        sc[t] += u;
        __syncthreads();
    }
    int ex = sc[t] - (a + b2);
    int n0 = p * PSZ + 2 * t;
    if (n0 < N) {
        noffs[n0] = pb + ex;
        disv[n0]  = rsqrtf((float)(a + 1));
    }
    if (n0 + 1 < N) {
        noffs[n0 + 1] = pb + ex + a;
        disv[n0 + 1]  = rsqrtf((float)(b2 + 1));
    }
    __syncthreads();
    h[2 * t]     = ex;
    h[2 * t + 1] = ex + a;
    __syncthreads();
    for (int s = t; s < len; s += 256) {
        unsigned w = pairs1[pb + s];
        int r = atomicAdd(&h[(w >> 17) & (PSZ - 1)], 1);
        pairs2[pb + r] = (int)(w & 0x1FFFFu);
    }
}

// ---------------- g = fp16((x @ W) * dis[row])  — MFMA ----------------
template <bool FP16IN>
__global__ __launch_bounds__(256) void k_gemm(const void* __restrict__ xv,
                                              const float* __restrict__ W,
                                              const float* __restrict__ disv,
                                              __half* __restrict__ g, int N) {
    int lane = threadIdx.x & 63;
    int wave = (blockIdx.x * 256 + threadIdx.x) >> 6;
    int nw   = (gridDim.x * 256) >> 6;
    int col  = lane & 15;
    int krow = (lane >> 4) * 8;

    half8 bf[2][4];
#pragma unroll
    for (int s = 0; s < 2; ++s)
#pragma unroll
        for (int n = 0; n < 4; ++n)
#pragma unroll
            for (int e = 0; e < 8; ++e)
                bf[s][n][e] = (_Float16)W[(size_t)(krow + e + s * 32) * DD + n * 16 + col];

    int nch = (N + 15) >> 4;
    for (int c = wave; c < nch; c += nw) {
        int base = c * 16;
        int arow = min(base + (lane & 15), N - 1);
        half8 af[2];
        if constexpr (FP16IN) {
            const __half* xr = (const __half*)xv + (size_t)arow * DD + krow;
#pragma unroll
            for (int s = 0; s < 2; ++s)
                af[s] = *(const half8*)(xr + s * 32);
        } else {
            const float* xr = (const float*)xv + (size_t)arow * DD + krow;
#pragma unroll
            for (int s = 0; s < 2; ++s) {
                float4 lo = *(const float4*)(xr + s * 32);
                float4 hi = *(const float4*)(xr + s * 32 + 4);
                af[s][0] = (_Float16)lo.x; af[s][1] = (_Float16)lo.y;
                af[s][2] = (_Float16)lo.z; af[s][3] = (_Float16)lo.w;
                af[s][4] = (_Float16)hi.x; af[s][5] = (_Float16)hi.y;
                af[s][6] = (_Float16)hi.z; af[s][7] = (_Float16)hi.w;
            }
        }
        floatx4 acc[4] = {{0.f, 0.f, 0.f, 0.f}, {0.f, 0.f, 0.f, 0.f},
                          {0.f, 0.f, 0.f, 0.f}, {0.f, 0.f, 0.f, 0.f}};
#pragma unroll
        for (int s = 0; s < 2; ++s)
#pragma unroll
            for (int n = 0; n < 4; ++n)
                acc[n] = __builtin_amdgcn_mfma_f32_16x16x32_f16(af[s], bf[s][n],
                                                                acc[n], 0, 0, 0);
#pragma unroll
        for (int j = 0; j < 4; ++j) {
            int rr = base + (lane >> 4) * 4 + j;
            if (rr < N) {
                float dv = disv[rr];
#pragma unroll
                for (int n = 0; n < 4; ++n)
                    g[(size_t)rr * DD + n * 16 + col] = __float2half(acc[n][j] * dv);
            }
        }
    }
}

// ---------------- fused aggregate + finalize + pooling (register acc) --------
// r12 proven config: CHUNK=16, staged pk + guarded dual-load + cross-node
// pk prefetch. gacc is PER-LAYER (deferred pooling fold).
template <bool FP16OUT>
__global__ __launch_bounds__(256) void k_agg(const int* __restrict__ pairs2,
                                             const int* __restrict__ noffs,
                                             const __half* __restrict__ g,
                                             const float* __restrict__ disv,
                                             const float* __restrict__ bbias,
                                             const int* __restrict__ batch,
                                             void* __restrict__ xoutv,
                                             float* __restrict__ gacc, int N) {
    int lane = threadIdx.x & 63;
    int g4   = lane >> 4;
    int l16  = lane & 15;
    int wave = (blockIdx.x * 256 + threadIdx.x) >> 6;
    int nw   = (gridDim.x * 256) >> 6;
    int NB   = (N + CHUNK - 1) / CHUNK;
    float4 bj = *(const float4*)&bbias[4 * l16];
    const char* gb = (const char*)g;
    for (int bu = wave; bu < NB; bu += nw) {
        int nbase = bu * CHUNK;
        int nend  = min(nbase + CHUNK, N);
        int nn    = nend - nbase;
        int nf  = noffs[nbase + min(lane, nn)];
        int bch = batch[nbase + min(lane, nn - 1)];
        float4 vmax = {0.f, 0.f, 0.f, 0.f}, vsum = {0.f, 0.f, 0.f, 0.f};
        int curg = __shfl(bch, 0);
        // prologue: prefetch node 0's first edge-index block
        int ps0  = __shfl(nf, 0);
        int pcnt = __shfl(nf, 1) - ps0;
        int pkpre = (lane < min(pcnt, 64)) ? pairs2[ps0 + lane] : 0;
        for (int i = 0; i < nn; ++i) {
            int pk   = pkpre;
            int s0   = ps0;
            int cnt  = pcnt;
            if (i + 1 < nn) {   // prefetch next node's block (independent of gathers)
                int ns0  = __shfl(nf, i + 1);
                int ncnt = __shfl(nf, i + 2) - ns0;
                pkpre = (lane < min(ncnt, 64)) ? pairs2[ns0 + lane] : 0;
                ps0 = ns0;
                pcnt = ncnt;
            }
            float4 acc = {0.f, 0.f, 0.f, 0.f};
            if (g4 == 0) {   // self-loop row
                uint2 rv = *(const uint2*)(gb + ((size_t)(nbase + i) * 128 + l16 * 8));
                float2 f0 = __half22float2(*(const __half2*)&rv.x);
                float2 f1 = __half22float2(*(const __half2*)&rv.y);
                acc.x = f0.x; acc.y = f0.y; acc.z = f1.x; acc.w = f1.y;
            }
            int kk0 = min(cnt, 64);
            int j = 0;
            for (; j + 8 <= kk0; j += 8) {   // guard-free dual-issue path
                int sA = __shfl(pk, j + g4);
                int sB = __shfl(pk, j + 4 + g4);
                uint2 rA = *(const uint2*)(gb + ((size_t)sA * 128 + l16 * 8));
                uint2 rB = *(const uint2*)(gb + ((size_t)sB * 128 + l16 * 8));
                float2 a0 = __half22float2(*(const __half2*)&rA.x);
                float2 a1 = __half22float2(*(const __half2*)&rA.y);
                float2 b0 = __half22float2(*(const __half2*)&rB.x);
                float2 b1 = __half22float2(*(const __half2*)&rB.y);
                acc.x += a0.x + b0.x;
                acc.y += a0.y + b0.y;
                acc.z += a1.x + b1.x;
                acc.w += a1.y + b1.y;
            }
            for (; j < kk0; j += 4) {        // guarded remainder
                int idx  = j + g4;
                int sidx = __shfl(pk, idx);
                if (idx < kk0) {
                    uint2 rv = *(const uint2*)(gb + ((size_t)sidx * 128 + l16 * 8));
                    float2 f0 = __half22float2(*(const __half2*)&rv.x);
                    float2 f1 = __half22float2(*(const __half2*)&rv.y);
                    acc.x += f0.x; acc.y += f0.y; acc.z += f1.x; acc.w += f1.y;
                }
            }
            // rare tail: degree > 64
            for (int k = 64; k < cnt; k += 64) {
                int kk = min(cnt - k, 64);
                int pkx = (lane < kk) ? pairs2[s0 + k + lane] : 0;
                for (int jj = 0; jj < kk; jj += 4) {
                    int idx  = jj + g4;
                    int sidx = __shfl(pkx, idx);
                    if (idx < kk) {
                        uint2 rv = *(const uint2*)(gb + ((size_t)sidx * 128 + l16 * 8));
                        float2 f0 = __half22float2(*(const __half2*)&rv.x);
                        float2 f1 = __half22float2(*(const __half2*)&rv.y);
                        acc.x += f0.x; acc.y += f0.y; acc.z += f1.x; acc.w += f1.y;
                    }
                }
            }
            acc.x += __shfl_xor(acc.x, 16);
            acc.y += __shfl_xor(acc.y, 16);
            acc.z += __shfl_xor(acc.z, 16);
            acc.w += __shfl_xor(acc.w, 16);
            acc.x += __shfl_xor(acc.x, 32);
            acc.y += __shfl_xor(acc.y, 32);
            acc.z += __shfl_xor(acc.z, 32);
            acc.w += __shfl_xor(acc.w, 32);
            float dv = disv[nbase + i];
            float4 v;
            v.x = fmaxf(fmaf(dv, acc.x, bj.x), 0.f);
            v.y = fmaxf(fmaf(dv, acc.y, bj.y), 0.f);
            v.z = fmaxf(fmaf(dv, acc.z, bj.z), 0.f);
            v.w = fmaxf(fmaf(dv, acc.w, bj.w), 0.f);
            if (g4 == 0) {
                if constexpr (FP16OUT) {
                    __half2 h0 = __float22half2_rn({v.x, v.y});
                    __half2 h1 = __float22half2_rn({v.z, v.w});
                    uint2 pkd = {*(unsigned*)&h0, *(unsigned*)&h1};
                    *(uint2*)((__half*)xoutv + (size_t)(nbase + i) * DD + 4 * l16) = pkd;
                } else {
                    *(float4*)((float*)xoutv + (size_t)(nbase + i) * DD + 4 * l16) = v;
                }
            }
            int gid = __shfl(bch, i);
            if (gid != curg) {
                if (g4 == 0) {
                    atomicMax((unsigned*)&gacc[curg * 128 + 4 * l16 + 0], __float_as_uint(vmax.x));
                    atomicMax((unsigned*)&gacc[curg * 128 + 4 * l16 + 1], __float_as_uint(vmax.y));
                    atomicMax((unsigned*)&gacc[curg * 128 + 4 * l16 + 2], __float_as_uint(vmax.z));
                    atomicMax((unsigned*)&gacc[curg * 128 + 4 * l16 + 3], __float_as_uint(vmax.w));
                    atomicAdd(&gacc[curg * 128 + 64 + 4 * l16 + 0], vsum.x);
                    atomicAdd(&gacc[curg * 128 + 64 + 4 * l16 + 1], vsum.y);
                    atomicAdd(&gacc[curg * 128 + 64 + 4 * l16 + 2], vsum.z);
                    atomicAdd(&gacc[curg * 128 + 64 + 4 * l16 + 3], vsum.w);
                }
                vmax = {0.f, 0.f, 0.f, 0.f};
                vsum = {0.f, 0.f, 0.f, 0.f};
                curg = gid;
            }
            vmax.x = fmaxf(vmax.x, v.x);
            vmax.y = fmaxf(vmax.y, v.y);
            vmax.z = fmaxf(vmax.z, v.z);
            vmax.w = fmaxf(vmax.w, v.w);
            vsum.x += v.x; vsum.y += v.y; vsum.z += v.z; vsum.w += v.w;
        }
        if (g4 == 0) {
            atomicMax((unsigned*)&gacc[curg * 128 + 4 * l16 + 0], __float_as_uint(vmax.x));
            atomicMax((unsigned*)&gacc[curg * 128 + 4 * l16 + 1], __float_as_uint(vmax.y));
            atomicMax((unsigned*)&gacc[curg * 128 + 4 * l16 + 2], __float_as_uint(vmax.z));
            atomicMax((unsigned*)&gacc[curg * 128 + 4 * l16 + 3], __float_as_uint(vmax.w));
            atomicAdd(&gacc[curg * 128 + 64 + 4 * l16 + 0], vsum.x);
            atomicAdd(&gacc[curg * 128 + 64 + 4 * l16 + 1], vsum.y);
            atomicAdd(&gacc[curg * 128 + 64 + 4 * l16 + 2], vsum.z);
            atomicAdd(&gacc[curg * 128 + 64 + 4 * l16 + 3], vsum.w);
        }
    }
}

// ---------------- final pooling fold: sum 3 per-layer gacc -> d_out graph part
__global__ __launch_bounds__(256) void k_poolF(const float* __restrict__ gacc,
                                               const int* __restrict__ cntI,
                                               float* __restrict__ outg) {
    int i = blockIdx.x * 256 + threadIdx.x;
    if (i < GG * 2 * DD) {
        int gidx = i >> 7;
        int j    = i & 127;
        float v = gacc[i] + gacc[GG * 2 * DD + i] + gacc[2 * GG * 2 * DD + i];
        if (j >= DD) v = v / (float)cntI[gidx];
        outg[i] = v;
    }
}

extern "C" void kernel_launch(void* const* d_in, const int* in_sizes, int n_in,
                              void* d_out, int out_size, void* d_ws, size_t ws_size,
                              hipStream_t stream) {
    const float* x     = (const float*)d_in[0];
    const int*   ei    = (const int*)d_in[1];
    const int*   batch = (const int*)d_in[2];

    int N = in_sizes[0] / DD;
    int E = in_sizes[1] / 2;
    const int* src = ei;
    const int* dst = ei + E;

    size_t nd  = (size_t)N * DD;
    int NPART  = (N + PSZ - 1) >> PBITS;
    int NB     = (N + CHUNK - 1) / CHUNK;
    int nb     = (E + EPB - 1) / EPB;

    float*    ws     = (float*)d_ws;
    float*    bufX   = ws;                            // N*DD (f32-sized; fp16 used)
    __half*   bufX16 = (__half*)bufX;
    __half*   bufG   = (__half*)(ws + nd);            // N*DD fp16
    float*    disv   = ws + nd + nd / 2;              // N
    float*    gacc   = disv + N;                      // 3 * GG*2*DD (per-layer)
    int*      cntI   = (int*)(gacc + 3 * GG * 2 * DD);  // GG
    int*      poffs  = cntI + GG;                     // 257
    int*      ptot   = poffs + 257;                   // 256
    int*      noffs  = ptot + 256;                    // N+1
    int*      bcnt   = noffs + N + 1;                 // 256*nb (raw, transposed)
    int*      bpre   = bcnt + 256 * nb;               // 256*nb (col prefix)
    unsigned* pairs1 = (unsigned*)(bpre + 256 * nb);  // E
    int*      pairs2 = (int*)(pairs1 + E);            // E

    hipMemsetAsync(gacc, 0, (size_t)3 * GG * 2 * DD * sizeof(float), stream);
    hipMemsetAsync(cntI, 0, (size_t)GG * sizeof(int), stream);

    k_hist<<<nb, 512, 0, stream>>>(dst, E, nb, bcnt);
    k_scanCol<<<256, 256, 0, stream>>>(bcnt, nb, bpre, ptot);
    k_scanP<<<1, 256, 0, stream>>>(ptot, poffs, noffs, N, E);
    k_count_batch<<<(N + 255) / 256, 256, 0, stream>>>(batch, N, cntI);
    k_part1<<<nb, 512, 0, stream>>>(src, dst, E, nb, bcnt, bpre, poffs, pairs1);
    k_part2<<<NPART, 256, 0, stream>>>(pairs1, poffs, pairs2, noffs, disv, N);

    int aggGrid = (NB + 3) / 4;

    // layer 0: f32 in -> fp16 intermediate out
    k_gemm<false><<<400, 256, 0, stream>>>(x, (const float*)d_in[3], disv, bufG, N);
    k_agg<true><<<aggGrid, 256, 0, stream>>>(pairs2, noffs, bufG, disv,
                                             (const float*)d_in[4], batch, bufX16,
                                             gacc, N);
    // layer 1: fp16 in -> fp16 intermediate out
    k_gemm<true><<<400, 256, 0, stream>>>(bufX16, (const float*)d_in[5], disv, bufG, N);
    k_agg<true><<<aggGrid, 256, 0, stream>>>(pairs2, noffs, bufG, disv,
                                             (const float*)d_in[6], batch, bufX16,
                                             gacc + GG * 2 * DD, N);
    // layer 2: fp16 in -> f32 final out
    k_gemm<true><<<400, 256, 0, stream>>>(bufX16, (const float*)d_in[7], disv, bufG, N);
    k_agg<false><<<aggGrid, 256, 0, stream>>>(pairs2, noffs, bufG, disv,
                                              (const float*)d_in[8], batch, d_out,
                                              gacc + 2 * GG * 2 * DD, N);

    k_poolF<<<(GG * 2 * DD + 255) / 256, 256, 0, stream>>>(gacc, cntI,
                                                           (float*)d_out + nd);
}